// Round 9
// baseline (1101.310 us; speedup 1.0000x reference)
//
#include <hip/hip_runtime.h>
#include <cstdint>
#include <cstddef>

#define JAX_PARTITIONABLE 1

namespace {

constexpr int Bsz = 16, Nn = 1024, Dd = 256, Kk = 16, Ss = 512;
constexpr uint32_t BN = (uint32_t)Bsz * Nn;                    // 16384
constexpr int ZQ_SIZE = Bsz * Nn * Dd;                          // 4194304
constexpr int PQ_OFF = ZQ_SIZE;
constexpr int PROB_OFF = ZQ_SIZE + 1;
constexpr int BNS = Bsz * Nn * Ss;                              // 8388608
constexpr int LP_OFF = PROB_OFF + BNS;

// workspace layout (float offsets)
constexpr int WS_CP = 0;                           // 256
constexpr int WS_B2 = 256;                         // K*S = 8192
constexpr int WS_WB2 = WS_B2 + Kk * Ss;            // B*S = 8192
constexpr int WS_WBF = WS_WB2 + Bsz * Ss;          // wbooks bf16 [b][s][d]: 2M shorts
constexpr int WS_BBF = WS_WBF + Bsz * Ss * Dd;     // books bf16
constexpr int WS_BTF = WS_BBF + (Kk * Ss * Dd) / 2; // bookT bf16 [k][d][s]
// total ~4.2M floats ~ 16.9 MB

constexpr float LOG2E = 1.4426950408889634f;

typedef __attribute__((ext_vector_type(8))) short bf16x8;
typedef __attribute__((ext_vector_type(4))) short short4v;
typedef __attribute__((ext_vector_type(4))) float f32x4;

// hw transcendental wrappers (v_exp_f32 / v_log_f32 are base-2)
__device__ __forceinline__ float hw_exp2(float x) { return __builtin_amdgcn_exp2f(x); }
__device__ __forceinline__ float hw_log2(float x) { return __builtin_amdgcn_logf(x); }

struct KP { uint32_t a, b; };

__host__ __device__ constexpr KP tf2x32(uint32_t k0, uint32_t k1,
                                        uint32_t x0, uint32_t x1) {
  uint32_t ks[3] = {k0, k1, k0 ^ k1 ^ 0x1BD11BDAu};
  const int rot[2][4] = {{13, 15, 26, 6}, {17, 29, 16, 24}};
  x0 += ks[0];
  x1 += ks[1];
#pragma unroll
  for (int i = 0; i < 5; ++i) {
#pragma unroll
    for (int j = 0; j < 4; ++j) {
      int r = rot[i & 1][j];
      x0 += x1;
      x1 = (x1 << r) | (x1 >> (32 - r));
      x1 ^= x0;
    }
    x0 += ks[(i + 1) % 3];
    x1 += ks[(i + 2) % 3] + (uint32_t)(i + 1);
  }
  return {x0, x1};
}

#if JAX_PARTITIONABLE
constexpr KP KG1 = tf2x32(0u, 42u, 0u, 0u);
constexpr KP KG2 = tf2x32(0u, 42u, 0u, 1u);
#else
constexpr KP KH0 = tf2x32(0u, 42u, 0u, 2u);
constexpr KP KH1 = tf2x32(0u, 42u, 1u, 3u);
constexpr KP KG1 = {KH0.a, KH1.a};
constexpr KP KG2 = {KH0.b, KH1.b};
#endif

__device__ __forceinline__ float jax_gumbel(KP key, uint32_t idx, uint32_t half) {
#if JAX_PARTITIONABLE
  (void)half;
  KP h = tf2x32(key.a, key.b, 0u, idx);
  uint32_t bits = h.a ^ h.b;
#else
  uint32_t lo = idx < half ? idx : idx - half;
  KP h = tf2x32(key.a, key.b, lo, lo + half);
  uint32_t bits = idx < half ? h.a : h.b;
#endif
  float u = __uint_as_float((bits >> 9) | 0x3F800000u) - 1.0f;
  return -__logf(-__logf(u + 1e-10f) + 1e-10f);
}

// gumbel scaled into the exp2 softmax domain: returns g * 2 * log2e
// (= -2*log2(y), exact same quantity with one fewer rounding).
__device__ __forceinline__ float jax_gumbel_w2(KP key, uint32_t idx) {
  KP h = tf2x32(key.a, key.b, 0u, idx);
  uint32_t bits = h.a ^ h.b;
  float u = __uint_as_float((bits >> 9) | 0x3F800000u) - 1.0f;
  float y = -__logf(u + 1e-10f) + 1e-10f;
  return -2.0f * hw_log2(y);
}

__device__ __forceinline__ float prec_q(const float* p) {
  return 0.5f / fmaxf(1.0f + expf(p[0]), 1e-10f);
}

__device__ __forceinline__ short f2bf(float x) {  // RNE f32->bf16
  uint32_t u = __float_as_uint(x);
  uint32_t r = (u + 0x7FFFu + ((u >> 16) & 1u)) >> 16;
  return (short)r;
}

// ---------------- K1: c_probs (B,K) + precision_q ----------------
__global__ void __launch_bounds__(256) cprobs_kernel(
    const float* __restrict__ c_logits, const float* __restrict__ lpq,
    const float* __restrict__ lpq_cls, float* __restrict__ ws,
    float* __restrict__ out) {
  __shared__ float sl[256];
  const int t = threadIdx.x;
  const float pqc = prec_q(lpq_cls);
  float g = jax_gumbel(KG1, (uint32_t)t, 128u);
  sl[t] = (c_logits[t] * pqc + g) * 2.0f;  // /TEMP, TEMP=0.5
  __syncthreads();
  const int b = t >> 4;
  float m = -3.0e38f;
  for (int j = 0; j < 16; ++j) m = fmaxf(m, sl[b * 16 + j]);
  float sum = 0.f;
  for (int j = 0; j < 16; ++j) sum += expf(sl[b * 16 + j] - m);
  ws[WS_CP + t] = expf(sl[t] - m) / sum;
  if (t == 0) out[PQ_OFF] = prec_q(lpq);
}

// ---------------- K2: b2 (K*S) ----------------
__global__ void __launch_bounds__(256) norms_kernel(
    const float* __restrict__ books, float* __restrict__ ws) {
  const int row = blockIdx.x * 4 + (threadIdx.x >> 6);
  const int lane = threadIdx.x & 63;
  float4 v = ((const float4*)(books + (size_t)row * Dd))[lane];
  float s = v.x * v.x + v.y * v.y + v.z * v.z + v.w * v.w;
#pragma unroll
  for (int d = 1; d < 64; d <<= 1) s += __shfl_xor(s, d);
  if (lane == 0) ws[WS_B2 + row] = s;
}

// ---------------- K3: books -> bf16 + transposed bf16 ----------------
__global__ void __launch_bounds__(256) prep_kernel(
    const float* __restrict__ books, float* __restrict__ ws) {
  __shared__ short tile[16 * 256];
  const int k = blockIdx.x >> 5;
  const int s0 = (blockIdx.x & 31) << 4;
  short* bbf = (short*)(ws + WS_BBF);
  short* btf = (short*)(ws + WS_BTF);
  const int t = threadIdx.x;
#pragma unroll
  for (int i = 0; i < 4; ++i) {
    int idx = t + 256 * i;  // 0..1023
    int r = idx >> 6, dq = idx & 63;
    float4 v = ((const float4*)books)[(size_t)(k * Ss + s0 + r) * 64 + dq];
    short4v h = {f2bf(v.x), f2bf(v.y), f2bf(v.z), f2bf(v.w)};
    *(short4v*)&bbf[(size_t)(k * Ss + s0 + r) * 256 + dq * 4] = h;
    *(short4v*)&tile[r * 256 + dq * 4] = h;
  }
  __syncthreads();
  const int d = t;  // 0..255
  short vals[16];
#pragma unroll
  for (int r = 0; r < 16; ++r) vals[r] = tile[r * 256 + d];
  bf16x8 lo, hi;
#pragma unroll
  for (int r = 0; r < 8; ++r) { lo[r] = vals[r]; hi[r] = vals[r + 8]; }
  size_t base = ((size_t)(k * 256 + d)) * 512 + s0;
  *(bf16x8*)&btf[base] = lo;
  *(bf16x8*)&btf[base + 8] = hi;
}

// ---------------- K4: wbooks bf16 (B,S,D) and wb2 (B,S) ----------------
__global__ void __launch_bounds__(256) wbooks_kernel(
    const float* __restrict__ books, float* __restrict__ ws) {
  const int bs = blockIdx.x;           // b*512 + s
  const int b = bs >> 9, s = bs & 511;
  const int d = threadIdx.x;
  const float* cp = ws + WS_CP + b * 16;
  float acc = 0.f;
#pragma unroll
  for (int k = 0; k < 16; ++k)
    acc = fmaf(cp[k], books[((size_t)(k * Ss + s)) * Dd + d], acc);
  short* wbf = (short*)(ws + WS_WBF);
  wbf[((size_t)(b * Ss + s)) * Dd + d] = f2bf(acc);
  if (d == 0) {
    float a2 = 0.f;
#pragma unroll
    for (int k = 0; k < 16; ++k) a2 = fmaf(cp[k], ws[WS_B2 + k * Ss + s], a2);
    ws[WS_WB2 + b * Ss + s] = a2;
  }
}

// ---------------- K5+K6 merged, 16-row tiles, 256-thread blocks ----------------
// Phase-diversity design: time has been pinned ~700us across barrier count,
// VALU work, traffic, and tile size -> bound is phase serialization with too
// few independent barrier domains per SIMD. 256-thread blocks (4 waves) keep
// the per-wave footprint (~112 unified regs -> natural 4 waves/SIMD band, NO
// tightened launch bounds - rounds 1/4 spills came from the reg cap, not the
// tile) but give 4 blocks/CU: each SIMD hosts ~4 waves from ~4 DIFFERENT
// blocks, so one block's barrier/MFMA phases hide under others' VALU phases.
//   blockIdx < 1024: zq. Wave w: GEMM1 s in [w*128,(w+1)*128), st=0..7;
//   GEMM2 d in [w*64,(w+1)*64), dt=0..3. C-layout col=lane&15, row=q*4+reg.
//   blockIdx >= 1024: mlogits, same 16-row shape vs wbooks bf16.
__global__ void __launch_bounds__(256, 4) fused_kernel(
    const float* __restrict__ ze, const float* __restrict__ lpq,
    const float* __restrict__ ws, float* __restrict__ out) {
  __shared__ short ze_s[16 * 264];   // 8.4 KB
  __shared__ short enc_s[16 * 520];  // 16.6 KB (zq only)
  __shared__ float2 redms[16][5];    // [row][wave] (max,sum), padded
  __shared__ float cpk[16];
  // total ~25.8 KB -> 4 blocks/CU fits 103 KB of 160 KB

  const int t = threadIdx.x;
  const int w = t >> 6;              // 0..3
  const int lane = t & 63, c = lane & 15, q = lane >> 4;
  const float pq = prec_q(lpq);

  if (blockIdx.x < 1024) {
    // ================= zq path =================
    const int b = blockIdx.x >> 6;
    const int n0 = (blockIdx.x & 63) << 4;
    const short* bbf = (const short*)(ws + WS_BBF);
    const short* btf = (const short*)(ws + WS_BTF);
    const float* b2p = ws + WS_B2;
    const float ca = 4.f * pq * LOG2E;   // score -> w-domain scale
    const float cbs = -2.f * pq * LOG2E; // b2 fold

    if (t < 16) cpk[t] = ws[WS_CP + b * 16 + t];
#pragma unroll
    for (int i = 0; i < 4; ++i) {
      int idx = t + 256 * i;  // 0..1023
      int r = idx >> 6, dq = idx & 63;
      float4 v = ((const float4*)ze)[(size_t)(b * Nn + n0 + r) * 64 + dq];
      short4v h = {f2bf(v.x), f2bf(v.y), f2bf(v.z), f2bf(v.w)};
      *(short4v*)&ze_s[r * 264 + dq * 4] = h;
    }
    __syncthreads();

    f32x4 acc2[4];   // dt = 0..3
#pragma unroll
    for (int dt = 0; dt < 4; ++dt) acc2[dt] = (f32x4)(0.f);

    for (int k = 0; k < 16; ++k) {
      // ---- GEMM1: scores = ze . books[k]^T  (1 rt x 8 st)
      f32x4 acc1[8];
#pragma unroll
      for (int st = 0; st < 8; ++st) acc1[st] = (f32x4)(0.f);
      for (int dstep = 0; dstep < 8; ++dstep) {
        bf16x8 a0 = *(const bf16x8*)&ze_s[(c) * 264 + dstep * 32 + q * 8];
#pragma unroll
        for (int st = 0; st < 8; ++st) {
          bf16x8 bB = *(const bf16x8*)&bbf[((size_t)(k * Ss + w * 128 + st * 16 + c)) * 256 +
                                           dstep * 32 + q * 8];
          acc1[st] = __builtin_amdgcn_mfma_f32_16x16x32_bf16(a0, bB, acc1[st], 0, 0, 0);
        }
      }

      // ---- w-domain scores + gumbel in C-layout registers
      float cb[8];
#pragma unroll
      for (int st = 0; st < 8; ++st) cb[st] = cbs * b2p[k * Ss + w * 128 + st * 16 + c];
      float mx[4], sm[4];
#pragma unroll
      for (int reg = 0; reg < 4; ++reg) mx[reg] = -3.0e38f;
#pragma unroll
      for (int st = 0; st < 8; ++st)
#pragma unroll
        for (int reg = 0; reg < 4; ++reg) {
          int row = n0 + q * 4 + reg;
          uint32_t gi = ((uint32_t)(b * Nn + row) * (uint32_t)Kk + (uint32_t)k) * (uint32_t)Ss +
                        (uint32_t)(w * 128 + st * 16 + c);
          float gw = jax_gumbel_w2(KG2, gi);
          float v = fmaf(acc1[st][reg], ca, cb[st]) + gw;
          acc1[st][reg] = v;
          mx[reg] = fmaxf(mx[reg], v);
        }
#pragma unroll
      for (int m = 1; m < 16; m <<= 1)
#pragma unroll
        for (int reg = 0; reg < 4; ++reg)
          mx[reg] = fmaxf(mx[reg], __shfl_xor(mx[reg], m));
#pragma unroll
      for (int reg = 0; reg < 4; ++reg) sm[reg] = 0.f;
#pragma unroll
      for (int st = 0; st < 8; ++st)
#pragma unroll
        for (int reg = 0; reg < 4; ++reg) {
          float e = hw_exp2(acc1[st][reg] - mx[reg]);
          acc1[st][reg] = e;
          sm[reg] += e;
        }
#pragma unroll
      for (int m = 1; m < 16; m <<= 1)
#pragma unroll
        for (int reg = 0; reg < 4; ++reg) sm[reg] += __shfl_xor(sm[reg], m);
      if (c == 0) {
#pragma unroll
        for (int reg = 0; reg < 4; ++reg)
          redms[q * 4 + reg][w] = make_float2(mx[reg], sm[reg]);
      }
      __syncthreads();  // barA: red array complete; orders enc writes after
                        // all GEMM2(k-1) reads.

      // ---- distributed combine (4 waves) + normalized enc
      const float cpv = cpk[k];
#pragma unroll
      for (int reg = 0; reg < 4; ++reg) {
        int rl = q * 4 + reg;
        float M = mx[reg];
#pragma unroll
        for (int w2 = 0; w2 < 4; ++w2) M = fmaxf(M, redms[rl][w2].x);
        float T = 0.f;
#pragma unroll
        for (int w2 = 0; w2 < 4; ++w2)
          T = fmaf(redms[rl][w2].y, hw_exp2(redms[rl][w2].x - M), T);
        float scale = cpv * hw_exp2(mx[reg] - M) * __builtin_amdgcn_rcpf(T);
#pragma unroll
        for (int st = 0; st < 8; ++st)
          enc_s[rl * 520 + w * 128 + st * 16 + c] = f2bf(acc1[st][reg] * scale);
      }
      __syncthreads();  // barB: enc complete for GEMM2

      // ---- GEMM2: zq += enc . bookT[k]
      for (int ss = 0; ss < 16; ++ss) {
        bf16x8 a0 = *(const bf16x8*)&enc_s[(c) * 520 + ss * 32 + q * 8];
#pragma unroll
        for (int dt = 0; dt < 4; ++dt) {
          bf16x8 bB = *(const bf16x8*)&btf[((size_t)(k * 256 + w * 64 + dt * 16 + c)) * 512 +
                                           ss * 32 + q * 8];
          acc2[dt] = __builtin_amdgcn_mfma_f32_16x16x32_bf16(a0, bB, acc2[dt], 0, 0, 0);
        }
      }
    }

    // ---- epilogue: C-layout -> global zq
#pragma unroll
    for (int dt = 0; dt < 4; ++dt)
#pragma unroll
      for (int reg = 0; reg < 4; ++reg) {
        int row = n0 + q * 4 + reg;
        int d = w * 64 + dt * 16 + c;
        out[(size_t)(b * Nn + row) * Dd + d] = acc2[dt][reg];
      }
  } else {
    // ================= mlogits path (16 rows) =================
    const int mbid = blockIdx.x - 1024;
    const int b = mbid >> 6;
    const int n0 = (mbid & 63) << 4;
    const short* wbf = (const short*)(ws + WS_WBF);
    const float* wb2 = ws + WS_WB2;

#pragma unroll
    for (int i = 0; i < 4; ++i) {
      int idx = t + 256 * i;
      int r = idx >> 6, dq = idx & 63;
      float4 v = ((const float4*)ze)[(size_t)(b * Nn + n0 + r) * 64 + dq];
      short4v h = {f2bf(v.x), f2bf(v.y), f2bf(v.z), f2bf(v.w)};
      *(short4v*)&ze_s[r * 264 + dq * 4] = h;
    }
    __syncthreads();

    f32x4 acc1[8];
#pragma unroll
    for (int st = 0; st < 8; ++st) acc1[st] = (f32x4)(0.f);
    for (int dstep = 0; dstep < 8; ++dstep) {
      bf16x8 a0 = *(const bf16x8*)&ze_s[(c) * 264 + dstep * 32 + q * 8];
#pragma unroll
      for (int st = 0; st < 8; ++st) {
        bf16x8 bB = *(const bf16x8*)&wbf[((size_t)(b * Ss + w * 128 + st * 16 + c)) * 256 +
                                         dstep * 32 + q * 8];
        acc1[st] = __builtin_amdgcn_mfma_f32_16x16x32_bf16(a0, bB, acc1[st], 0, 0, 0);
      }
    }

    float mx[4], sm[4];
#pragma unroll
    for (int reg = 0; reg < 4; ++reg) mx[reg] = -3.0e38f;
#pragma unroll
    for (int st = 0; st < 8; ++st) {
      const float wb2v = wb2[b * Ss + w * 128 + st * 16 + c];
#pragma unroll
      for (int reg = 0; reg < 4; ++reg) {
        float v = (2.f * acc1[st][reg] - wb2v) * pq;
        acc1[st][reg] = v;
        mx[reg] = fmaxf(mx[reg], v);
      }
    }
#pragma unroll
    for (int m = 1; m < 16; m <<= 1)
#pragma unroll
      for (int reg = 0; reg < 4; ++reg)
        mx[reg] = fmaxf(mx[reg], __shfl_xor(mx[reg], m));
#pragma unroll
    for (int reg = 0; reg < 4; ++reg) sm[reg] = 0.f;
#pragma unroll
    for (int st = 0; st < 8; ++st)
#pragma unroll
      for (int reg = 0; reg < 4; ++reg)
        sm[reg] += __expf(acc1[st][reg] - mx[reg]);
#pragma unroll
    for (int m = 1; m < 16; m <<= 1)
#pragma unroll
      for (int reg = 0; reg < 4; ++reg) sm[reg] += __shfl_xor(sm[reg], m);
    if (c == 0) {
#pragma unroll
      for (int reg = 0; reg < 4; ++reg)
        redms[q * 4 + reg][w] = make_float2(mx[reg], sm[reg]);
    }
    __syncthreads();

#pragma unroll
    for (int reg = 0; reg < 4; ++reg) {
      int rl = q * 4 + reg;
      float M = mx[reg];
#pragma unroll
      for (int w2 = 0; w2 < 4; ++w2) M = fmaxf(M, redms[rl][w2].x);
      float T = 0.f;
#pragma unroll
      for (int w2 = 0; w2 < 4; ++w2)
        T = fmaf(redms[rl][w2].y, __expf(redms[rl][w2].x - M), T);
      const float invT = __builtin_amdgcn_rcpf(T);
      const float lT = __logf(T);
      const size_t base = (size_t)(b * Nn + n0 + rl) * Ss;
#pragma unroll
      for (int st = 0; st < 8; ++st) {
        int s = w * 128 + st * 16 + c;
        float v = acc1[st][reg] - M;
        out[PROB_OFF + base + s] = __expf(v) * invT;
        out[LP_OFF + base + s] = v - lT;
      }
    }
  }
}

}  // namespace

extern "C" void kernel_launch(void* const* d_in, const int* in_sizes, int n_in,
                              void* d_out, int out_size, void* d_ws, size_t ws_size,
                              hipStream_t stream) {
  (void)in_sizes; (void)n_in; (void)out_size; (void)ws_size;
  const float* ze = (const float*)d_in[0];
  const float* c_logits = (const float*)d_in[1];
  const float* books = (const float*)d_in[2];
  const float* lpq = (const float*)d_in[3];
  const float* lpq_cls = (const float*)d_in[4];
  float* out = (float*)d_out;
  float* ws = (float*)d_ws;

  hipLaunchKernelGGL(cprobs_kernel, dim3(1), dim3(256), 0, stream,
                     c_logits, lpq, lpq_cls, ws, out);
  hipLaunchKernelGGL(norms_kernel, dim3(Kk * Ss / 4), dim3(256), 0, stream, books, ws);
  hipLaunchKernelGGL(prep_kernel, dim3(Kk * 32), dim3(256), 0, stream, books, ws);
  hipLaunchKernelGGL(wbooks_kernel, dim3(Bsz * Ss), dim3(256), 0, stream, books, ws);
  hipLaunchKernelGGL(fused_kernel, dim3(2048), dim3(256), 0, stream,
                     ze, lpq, ws, out);
}